// Round 8
// baseline (308.353 us; speedup 1.0000x reference)
//
#include <hip/hip_runtime.h>
#include <hip/hip_bf16.h>

#define NEG_SLOPE 0.2f

typedef __attribute__((ext_vector_type(8))) short bf16x8;
typedef __attribute__((ext_vector_type(4))) float f32x4;

__device__ __forceinline__ void gload_lds16(const void* g, void* l) {
    __builtin_amdgcn_global_load_lds((const __attribute__((address_space(1))) void*)g,
                                     (__attribute__((address_space(3))) void*)l,
                                     16, 0, 0);
}
__device__ __forceinline__ float bflo(unsigned int u) {
    return __uint_as_float(u << 16);
}
__device__ __forceinline__ float bfhi(unsigned int u) {
    return __uint_as_float(u & 0xffff0000u);
}
__device__ __forceinline__ unsigned short f2bf(float f) {
    __hip_bfloat16 h = __float2bfloat16(f);
    return *reinterpret_cast<unsigned short*>(&h);
}

// ---------------- CSR build + conversions ----------------

// combined: [0,totPrep) conversion work, [totPrep, totPrep+E) histogram
__global__ void k_prep(const float* __restrict__ x, const float* __restrict__ W0,
                       const float* __restrict__ W1, const float* __restrict__ W2,
                       __hip_bfloat16* __restrict__ xb, __hip_bfloat16* __restrict__ W0t,
                       __hip_bfloat16* __restrict__ W1t, __hip_bfloat16* __restrict__ W2t,
                       const int* __restrict__ ei, int* __restrict__ counts, int E,
                       int N, int K0, int totA, int totPrep) {
    int i = blockIdx.x * blockDim.x + threadIdx.x;
    if (i >= totPrep) {
        int e = i - totPrep;
        if (e < E) atomicAdd(&counts[ei[E + e]], 1);
        return;
    }
    if (i < totA) {
        int r = i / K0;
        xb[i] = __float2bfloat16(r < N ? x[i] : 0.f);
        return;
    }
    i -= totA;
    if (i < K0 * 256) {
        int c = i / K0, k = i - c * K0;
        W0t[i] = __float2bfloat16(W0[k * 256 + c]);
        return;
    }
    i -= K0 * 256;
    if (i < 65536) {
        int c = i >> 8, k = i & 255;
        W1t[i] = __float2bfloat16(W1[k * 256 + c]);
        return;
    }
    i -= 65536;
    if (i < 65536) {
        int c = i >> 8, k = i & 255;
        W2t[i] = __float2bfloat16(W2[k * 256 + c]);
    }
}

// chunked scan over (counts[i]+1) -> rowptr[0..n]; +1 = self loop
__global__ __launch_bounds__(1024) void k_scan(const int* __restrict__ counts,
                                               int* __restrict__ rowptr, int n) {
    __shared__ int wsum[16];
    __shared__ int wpre[16];
    int t = threadIdx.x;
    int chunk = (n + 1023) >> 10;
    int lo = t * chunk, hi = min(lo + chunk, n);
    if (lo > n) lo = n;
    if (hi < lo) hi = lo;
    int s = 0;
    for (int i = lo; i < hi; ++i) s += counts[i] + 1;
    int lane = t & 63, w = t >> 6;
    int v = s;
#pragma unroll
    for (int off = 1; off < 64; off <<= 1) {
        int u = __shfl_up(v, off);
        if (lane >= off) v += u;
    }
    if (lane == 63) wsum[w] = v;
    __syncthreads();
    if (w == 0 && lane < 16) {
        int x = wsum[lane];
#pragma unroll
        for (int off = 1; off < 16; off <<= 1) {
            int u = __shfl_up(x, off);
            if (lane >= off) x += u;
        }
        wpre[lane] = x - wsum[lane];
    }
    __syncthreads();
    int run = wpre[w] + v - s;
    for (int i = lo; i < hi; ++i) { rowptr[i] = run; run += counts[i] + 1; }
    if (t == 1023) rowptr[n] = run;
}

// self loop at slot rowptr[d]; edges at rowptr[d]+1+cursor
__global__ void k_scatter(const int* __restrict__ ei, int E, int n,
                          const int* __restrict__ rowptr, int* __restrict__ cursor,
                          int* __restrict__ csrc) {
    int i = blockIdx.x * blockDim.x + threadIdx.x;
    int tot = E + n;
    if (i >= tot) return;
    if (i >= E) {
        int d = i - E;
        csrc[rowptr[d]] = d;
    } else {
        int s = ei[i], d = ei[E + i];
        int pos = rowptr[d] + 1 + atomicAdd(&cursor[d], 1);
        csrc[pos] = s;
    }
}

// ---------------- bf16 MFMA GEMM: C[Mpad,256] = A[Mpad,K] @ Bt[256,K]^T ----------------

__global__ __launch_bounds__(256) void k_gemm_mfma(
    const __hip_bfloat16* __restrict__ A,   // [Mpad][K]
    const __hip_bfloat16* __restrict__ Bt,  // [NC][K]
    __hip_bfloat16* __restrict__ Cb,        // [Mpad][NC]
    int K, int NC)
{
    __shared__ __hip_bfloat16 As[128 * 32];
    __shared__ __hip_bfloat16 Bs[128 * 32];
    int tid = threadIdx.x;
    int lane = tid & 63, w = tid >> 6;
    int wm = w >> 1, wn = w & 1;
    int rr = lane & 15, kg = lane >> 4;
    int bm = blockIdx.x * 128, bn = blockIdx.y * 128;

    f32x4 acc[4][4] = {};

    for (int k0 = 0; k0 < K; k0 += 32) {
#pragma unroll
        for (int s = 0; s < 2; ++s) {
            int c = tid + s * 256;
            int r = c >> 2, sl = c & 3;
            int ksrc = k0 + 8 * (sl ^ ((r >> 1) & 3));
            char* dstA = ((char*)As) + s * 4096 + w * 1024;
            char* dstB = ((char*)Bs) + s * 4096 + w * 1024;
            gload_lds16(A + (size_t)(bm + r) * K + ksrc, dstA);
            gload_lds16(Bt + (size_t)(bn + r) * K + ksrc, dstB);
        }
        __syncthreads();
        bf16x8 af[4], bfr[4];
#pragma unroll
        for (int i = 0; i < 4; ++i) {
            int row = wm * 64 + i * 16 + rr;
            af[i] = *(const bf16x8*)((const char*)As + row * 64 + ((kg ^ ((row >> 1) & 3)) << 4));
        }
#pragma unroll
        for (int j = 0; j < 4; ++j) {
            int col = wn * 64 + j * 16 + rr;
            bfr[j] = *(const bf16x8*)((const char*)Bs + col * 64 + ((kg ^ ((col >> 1) & 3)) << 4));
        }
#pragma unroll
        for (int i = 0; i < 4; ++i)
#pragma unroll
            for (int j = 0; j < 4; ++j)
                acc[i][j] = __builtin_amdgcn_mfma_f32_16x16x32_bf16(af[i], bfr[j], acc[i][j], 0, 0, 0);
        __syncthreads();
    }
#pragma unroll
    for (int i = 0; i < 4; ++i) {
#pragma unroll
        for (int j = 0; j < 4; ++j) {
            int col = bn + wn * 64 + j * 16 + rr;
#pragma unroll
            for (int q = 0; q < 4; ++q) {
                int row = bm + wm * 64 + i * 16 + kg * 4 + q;
                Cb[(size_t)row * NC + col] = __float2bfloat16(acc[i][j][q]);
            }
        }
    }
}

// ---------------- attention coefficients from bf16 xl ----------------

__global__ __launch_bounds__(256) void k_attn(const __hip_bfloat16* __restrict__ xlb,
                                              const float* __restrict__ as_,
                                              const float* __restrict__ ad_,
                                              float* __restrict__ als,
                                              float* __restrict__ ald, int n) {
    int node = (int)(((size_t)blockIdx.x * blockDim.x + threadIdx.x) >> 6);
    if (node >= n) return;
    int lane = threadIdx.x & 63;
    uint2 xv = *(const uint2*)(xlb + (size_t)node * 256 + (lane << 2));
    float x0 = bflo(xv.x), x1 = bfhi(xv.x), x2 = bflo(xv.y), x3 = bfhi(xv.y);
    float4 sv = *reinterpret_cast<const float4*>(as_ + (lane << 2));
    float4 dv = *reinterpret_cast<const float4*>(ad_ + (lane << 2));
    float ps = x0 * sv.x + x1 * sv.y + x2 * sv.z + x3 * sv.w;
    float pd = x0 * dv.x + x1 * dv.y + x2 * dv.z + x3 * dv.w;
#pragma unroll
    for (int off = 1; off < 8; off <<= 1) {
        ps += __shfl_xor(ps, off);
        pd += __shfl_xor(pd, off);
    }
    if ((lane & 7) == 0) {
        als[node * 8 + (lane >> 3)] = ps;
        ald[node * 8 + (lane >> 3)] = pd;
    }
}

// -------- channel-split aggregation: 2 waves/node, 16 edges per iteration --------
// wave = (node, halfsel). lane = 16*eslot + l4; lane owns 8 channels
// ch0 = halfsel*128 + l4*8 (head = ch0>>5). Alphas are per-head so the two
// waves are independent. Self-loop logit anchors the exp shift (exact softmax,
// no online rescale). One iteration: 4 uint4 row-gathers/lane covering 16 edges.

#define FMA8(XV, AL)                                              \
    {                                                             \
        acc[0] += (AL) * bflo(XV.x); acc[1] += (AL) * bfhi(XV.x); \
        acc[2] += (AL) * bflo(XV.y); acc[3] += (AL) * bfhi(XV.y); \
        acc[4] += (AL) * bflo(XV.z); acc[5] += (AL) * bfhi(XV.z); \
        acc[6] += (AL) * bflo(XV.w); acc[7] += (AL) * bfhi(XV.w); \
    }

__global__ __launch_bounds__(256) void k_agg(const __hip_bfloat16* __restrict__ xlb,
                                             const float* __restrict__ als,
                                             const float* __restrict__ ald,
                                             const int* __restrict__ rowptr,
                                             const int* __restrict__ csrc,
                                             const float* __restrict__ bias,
                                             __hip_bfloat16* __restrict__ hb,
                                             const float* __restrict__ w3,
                                             float* __restrict__ xl3, int n) {
    __shared__ float part[4];
    int wid = threadIdx.x >> 6;
    int node = blockIdx.x * 2 + (wid >> 1);
    int halfsel = wid & 1;
    int lane = threadIdx.x & 63;
    int eslot = lane >> 4;
    int l4 = lane & 15;
    int ch0 = halfsel * 128 + (l4 << 3);
    int head = ch0 >> 5;
    bool active = node < n;

    float s = 0.f;
    float acc[8] = {};
    float o[8] = {};

    if (active) {
        int beg = rowptr[node];
        int deg = rowptr[node + 1] - beg;
        int dm1 = deg - 1;
        const __hip_bfloat16* xrow = xlb + ch0;
        const float* alsh = als + head;

        float aldv = ald[node * 8 + head];
        float m0 = als[node * 8 + head] + aldv;      // self-loop logit
        m0 = m0 > 0.f ? m0 : NEG_SLOPE * m0;         // exact exp-shift anchor

        for (int base = 0; base < deg; base += 16) {
            int e0 = base + eslot;
            int i0 = min(e0, dm1), i1 = min(e0 + 4, dm1);
            int i2 = min(e0 + 8, dm1), i3 = min(e0 + 12, dm1);
            int s0 = csrc[beg + i0];
            int s1 = csrc[beg + i1];
            int s2 = csrc[beg + i2];
            int s3 = csrc[beg + i3];
            uint4 r0 = *(const uint4*)(xrow + ((size_t)s0 << 8));
            uint4 r1 = *(const uint4*)(xrow + ((size_t)s1 << 8));
            uint4 r2 = *(const uint4*)(xrow + ((size_t)s2 << 8));
            uint4 r3 = *(const uint4*)(xrow + ((size_t)s3 << 8));
            float av0 = alsh[s0 * 8];
            float av1 = alsh[s1 * 8];
            float av2 = alsh[s2 * 8];
            float av3 = alsh[s3 * 8];
            float e_, a0, a1, a2, a3;
            e_ = av0 + aldv; e_ = e_ > 0.f ? e_ : NEG_SLOPE * e_;
            a0 = (e0 < deg) ? __expf(e_ - m0) : 0.f;
            e_ = av1 + aldv; e_ = e_ > 0.f ? e_ : NEG_SLOPE * e_;
            a1 = (e0 + 4 < deg) ? __expf(e_ - m0) : 0.f;
            e_ = av2 + aldv; e_ = e_ > 0.f ? e_ : NEG_SLOPE * e_;
            a2 = (e0 + 8 < deg) ? __expf(e_ - m0) : 0.f;
            e_ = av3 + aldv; e_ = e_ > 0.f ? e_ : NEG_SLOPE * e_;
            a3 = (e0 + 12 < deg) ? __expf(e_ - m0) : 0.f;
            s += (a0 + a1) + (a2 + a3);
            FMA8(r0, a0)
            FMA8(r1, a1)
            FMA8(r2, a2)
            FMA8(r3, a3)
        }
        // reduce over the 4 edge-slot groups (lanes with same l4)
        s += __shfl_xor(s, 16);
        s += __shfl_xor(s, 32);
#pragma unroll
        for (int c = 0; c < 8; ++c) {
            acc[c] += __shfl_xor(acc[c], 16);
            acc[c] += __shfl_xor(acc[c], 32);
        }
        float inv = 1.f / (s + 1e-16f);
        float4 bv0 = *reinterpret_cast<const float4*>(bias + ch0);
        float4 bv1 = *reinterpret_cast<const float4*>(bias + ch0 + 4);
        o[0] = acc[0] * inv + bv0.x; o[1] = acc[1] * inv + bv0.y;
        o[2] = acc[2] * inv + bv0.z; o[3] = acc[3] * inv + bv0.w;
        o[4] = acc[4] * inv + bv1.x; o[5] = acc[5] * inv + bv1.y;
        o[6] = acc[6] * inv + bv1.z; o[7] = acc[7] * inv + bv1.w;
#pragma unroll
        for (int c = 0; c < 8; ++c) o[c] = o[c] > 0.f ? o[c] : expm1f(o[c]);
    }

    if (w3) {
        // fused layer-3 matvec: p summed over the 16 l4-lanes of THIS eslot group
        // (o identical across eslot groups after the acc reduction) -> full half-dot,
        // no duplication, no extra scaling.
        float p = 0.f;
        if (active) {
#pragma unroll
            for (int c = 0; c < 8; ++c) p += o[c] * w3[ch0 + c];
        }
#pragma unroll
        for (int off = 1; off < 16; off <<= 1) p += __shfl_xor(p, off);
        if (lane == 0) part[wid] = p;
        __syncthreads();
        if (active && lane == 0 && halfsel == 0)
            xl3[node] = part[wid] + part[wid + 1];
    } else if (active && eslot == 0) {
        uint4 ov;
        ov.x = (unsigned)f2bf(o[0]) | ((unsigned)f2bf(o[1]) << 16);
        ov.y = (unsigned)f2bf(o[2]) | ((unsigned)f2bf(o[3]) << 16);
        ov.z = (unsigned)f2bf(o[4]) | ((unsigned)f2bf(o[5]) << 16);
        ov.w = (unsigned)f2bf(o[6]) | ((unsigned)f2bf(o[7]) << 16);
        *(uint4*)(hb + (size_t)node * 256 + ch0) = ov;
    }
}

// ---------------- layer 3 final ----------------

__global__ __launch_bounds__(256) void k_final(const float* __restrict__ xl3,
                                               const int* __restrict__ rowptr,
                                               const int* __restrict__ csrc,
                                               const float* __restrict__ as3,
                                               const float* __restrict__ ad3,
                                               const float* __restrict__ b3,
                                               float* __restrict__ out, int n) {
    int node = (int)(((size_t)blockIdx.x * blockDim.x + threadIdx.x) >> 6);
    if (node >= n) return;
    int lane = threadIdx.x & 63;
    int beg = rowptr[node];
    int deg = rowptr[node + 1] - beg;
    float a_s = as3[0], a_d = ad3[0], bb = b3[0];
    float xself = xl3[node];
    float dterm = a_d * xself;
    float m0 = a_s * xself + dterm;                 // self-loop logit anchor
    m0 = m0 > 0.f ? m0 : NEG_SLOPE * m0;
    float s = 0.f, wv = 0.f;
    for (int ee = lane; ee < deg; ee += 64) {
        int sidx = csrc[beg + ee];
        float xs = xl3[sidx];
        float e = a_s * xs + dterm;
        e = e > 0.f ? e : NEG_SLOPE * e;
        float ex = __expf(e - m0);
        s += ex;
        wv += ex * xs;
    }
#pragma unroll
    for (int off = 1; off < 64; off <<= 1) {
        s += __shfl_xor(s, off);
        wv += __shfl_xor(wv, off);
    }
    if (lane == 0) out[node] = wv / (s + 1e-16f) + bb;
}

// ---------------- launcher ----------------

extern "C" void kernel_launch(void* const* d_in, const int* in_sizes, int n_in,
                              void* d_out, int out_size, void* d_ws, size_t ws_size,
                              hipStream_t stream) {
    const float* x   = (const float*)d_in[0];
    const int*   ei  = (const int*)d_in[1];
    const float* W0  = (const float*)d_in[2];
    const float* as0 = (const float*)d_in[3];
    const float* ad0 = (const float*)d_in[4];
    const float* b0  = (const float*)d_in[5];
    const float* W1  = (const float*)d_in[6];
    const float* as1 = (const float*)d_in[7];
    const float* ad1 = (const float*)d_in[8];
    const float* b1  = (const float*)d_in[9];
    const float* W2  = (const float*)d_in[10];
    const float* as2 = (const float*)d_in[11];
    const float* ad2 = (const float*)d_in[12];
    const float* b2  = (const float*)d_in[13];
    const float* W3  = (const float*)d_in[14];
    const float* as3 = (const float*)d_in[15];
    const float* ad3 = (const float*)d_in[16];
    const float* b3  = (const float*)d_in[17];

    int N    = in_sizes[0] / 64;   // 30000
    int E    = in_sizes[1] / 2;    // 480000
    int K0   = in_sizes[2] / 256;  // 64
    int Npad = (N + 127) & ~127;   // 30080

    char* ws = (char*)d_ws;
    auto alloc = [&](size_t bytes) {
        char* p = ws;
        ws += (bytes + 255) & ~(size_t)255;
        return p;
    };
    int* rowptr = (int*)alloc((size_t)(N + 1) * 4);
    int* cc     = (int*)alloc((size_t)2 * N * 4);  // cursor | counts
    int* cursor = cc;
    int* counts = cc + N;
    int* csrc   = (int*)alloc((size_t)(E + N) * 4);
    __hip_bfloat16* xb  = (__hip_bfloat16*)alloc((size_t)Npad * K0 * 2);
    __hip_bfloat16* W0t = (__hip_bfloat16*)alloc((size_t)K0 * 256 * 2);
    __hip_bfloat16* W1t = (__hip_bfloat16*)alloc((size_t)256 * 256 * 2);
    __hip_bfloat16* W2t = (__hip_bfloat16*)alloc((size_t)256 * 256 * 2);
    __hip_bfloat16* xlb = (__hip_bfloat16*)alloc((size_t)Npad * 256 * 2);
    __hip_bfloat16* hb  = (__hip_bfloat16*)alloc((size_t)Npad * 256 * 2);
    float* als = (float*)alloc((size_t)N * 8 * 4);
    float* ald = (float*)alloc((size_t)N * 8 * 4);
    float* xl3 = (float*)alloc((size_t)N * 4);

    hipMemsetAsync(cc, 0, (size_t)2 * N * 4, stream);
    hipMemsetAsync(hb + (size_t)N * 256, 0, (size_t)(Npad - N) * 256 * 2, stream);

    int totA = Npad * K0;
    int totPrep = totA + K0 * 256 + 65536 + 65536;
    k_prep<<<(totPrep + E + 255) / 256, 256, 0, stream>>>(x, W0, W1, W2, xb, W0t, W1t, W2t,
                                                          ei, counts, E, N, K0, totA, totPrep);
    k_scan<<<1, 1024, 0, stream>>>(counts, rowptr, N);
    k_scatter<<<(E + N + 255) / 256, 256, 0, stream>>>(ei, E, N, rowptr, cursor, csrc);

    int nwb = (N + 3) / 4;        // k_attn/k_final: 1 wave/node, 4 waves/block
    int nab = (N + 1) / 2;        // k_agg: 2 waves/node, 2 nodes/block
    dim3 ggrid(Npad / 128, 2);

    // layer 0
    k_gemm_mfma<<<ggrid, 256, 0, stream>>>(xb, W0t, xlb, K0, 256);
    k_attn<<<nwb, 256, 0, stream>>>(xlb, as0, ad0, als, ald, N);
    k_agg<<<nab, 256, 0, stream>>>(xlb, als, ald, rowptr, csrc, b0, hb, nullptr, nullptr, N);
    // layer 1
    k_gemm_mfma<<<ggrid, 256, 0, stream>>>(hb, W1t, xlb, 256, 256);
    k_attn<<<nwb, 256, 0, stream>>>(xlb, as1, ad1, als, ald, N);
    k_agg<<<nab, 256, 0, stream>>>(xlb, als, ald, rowptr, csrc, b1, hb, nullptr, nullptr, N);
    // layer 2 (+ fused layer-3 matvec)
    k_gemm_mfma<<<ggrid, 256, 0, stream>>>(hb, W2t, xlb, 256, 256);
    k_attn<<<nwb, 256, 0, stream>>>(xlb, as2, ad2, als, ald, N);
    k_agg<<<nab, 256, 0, stream>>>(xlb, als, ald, rowptr, csrc, b2, hb, W3, xl3, N);
    // layer 3
    k_final<<<nwb, 256, 0, stream>>>(xl3, rowptr, csrc, as3, ad3, b3, (float*)d_out, N);
}

// Round 9
// 278.020 us; speedup vs baseline: 1.1091x; 1.1091x over previous
//
#include <hip/hip_runtime.h>
#include <hip/hip_bf16.h>

#define NEG_SLOPE 0.2f

typedef __attribute__((ext_vector_type(8))) short bf16x8;
typedef __attribute__((ext_vector_type(4))) float f32x4;

__device__ __forceinline__ void gload_lds16(const void* g, void* l) {
    __builtin_amdgcn_global_load_lds((const __attribute__((address_space(1))) void*)g,
                                     (__attribute__((address_space(3))) void*)l,
                                     16, 0, 0);
}
__device__ __forceinline__ float bflo(unsigned int u) {
    return __uint_as_float(u << 16);
}
__device__ __forceinline__ float bfhi(unsigned int u) {
    return __uint_as_float(u & 0xffff0000u);
}
__device__ __forceinline__ unsigned short f2bf(float f) {
    __hip_bfloat16 h = __float2bfloat16(f);
    return *reinterpret_cast<unsigned short*>(&h);
}

// ---------------- CSR build + conversions ----------------

// combined: [0,totPrep) conversion work, [totPrep, totPrep+E) histogram
__global__ void k_prep(const float* __restrict__ x, const float* __restrict__ W0,
                       const float* __restrict__ W1, const float* __restrict__ W2,
                       __hip_bfloat16* __restrict__ xb, __hip_bfloat16* __restrict__ W0t,
                       __hip_bfloat16* __restrict__ W1t, __hip_bfloat16* __restrict__ W2t,
                       const int* __restrict__ ei, int* __restrict__ counts, int E,
                       int N, int K0, int totA, int totPrep) {
    int i = blockIdx.x * blockDim.x + threadIdx.x;
    if (i >= totPrep) {
        int e = i - totPrep;
        if (e < E) atomicAdd(&counts[ei[E + e]], 1);
        return;
    }
    if (i < totA) {
        int r = i / K0;
        xb[i] = __float2bfloat16(r < N ? x[i] : 0.f);
        return;
    }
    i -= totA;
    if (i < K0 * 256) {
        int c = i / K0, k = i - c * K0;
        W0t[i] = __float2bfloat16(W0[k * 256 + c]);
        return;
    }
    i -= K0 * 256;
    if (i < 65536) {
        int c = i >> 8, k = i & 255;
        W1t[i] = __float2bfloat16(W1[k * 256 + c]);
        return;
    }
    i -= 65536;
    if (i < 65536) {
        int c = i >> 8, k = i & 255;
        W2t[i] = __float2bfloat16(W2[k * 256 + c]);
    }
}

// chunked scan over (counts[i]+1) -> rowptr[0..n]; +1 = self loop
__global__ __launch_bounds__(1024) void k_scan(const int* __restrict__ counts,
                                               int* __restrict__ rowptr, int n) {
    __shared__ int wsum[16];
    __shared__ int wpre[16];
    int t = threadIdx.x;
    int chunk = (n + 1023) >> 10;
    int lo = t * chunk, hi = min(lo + chunk, n);
    if (lo > n) lo = n;
    if (hi < lo) hi = lo;
    int s = 0;
    for (int i = lo; i < hi; ++i) s += counts[i] + 1;
    int lane = t & 63, w = t >> 6;
    int v = s;
#pragma unroll
    for (int off = 1; off < 64; off <<= 1) {
        int u = __shfl_up(v, off);
        if (lane >= off) v += u;
    }
    if (lane == 63) wsum[w] = v;
    __syncthreads();
    if (w == 0 && lane < 16) {
        int x = wsum[lane];
#pragma unroll
        for (int off = 1; off < 16; off <<= 1) {
            int u = __shfl_up(x, off);
            if (lane >= off) x += u;
        }
        wpre[lane] = x - wsum[lane];
    }
    __syncthreads();
    int run = wpre[w] + v - s;
    for (int i = lo; i < hi; ++i) { rowptr[i] = run; run += counts[i] + 1; }
    if (t == 1023) rowptr[n] = run;
}

// self loop at slot rowptr[d]; edges at rowptr[d]+1+cursor
__global__ void k_scatter(const int* __restrict__ ei, int E, int n,
                          const int* __restrict__ rowptr, int* __restrict__ cursor,
                          int* __restrict__ csrc) {
    int i = blockIdx.x * blockDim.x + threadIdx.x;
    int tot = E + n;
    if (i >= tot) return;
    if (i >= E) {
        int d = i - E;
        csrc[rowptr[d]] = d;
    } else {
        int s = ei[i], d = ei[E + i];
        int pos = rowptr[d] + 1 + atomicAdd(&cursor[d], 1);
        csrc[pos] = s;
    }
}

// ---------------- bf16 MFMA GEMM: C[Mpad,256] = A[Mpad,K] @ Bt[256,K]^T ----------------

__global__ __launch_bounds__(256) void k_gemm_mfma(
    const __hip_bfloat16* __restrict__ A,   // [Mpad][K]
    const __hip_bfloat16* __restrict__ Bt,  // [NC][K]
    __hip_bfloat16* __restrict__ Cb,        // [Mpad][NC]
    int K, int NC)
{
    __shared__ __hip_bfloat16 As[128 * 32];
    __shared__ __hip_bfloat16 Bs[128 * 32];
    int tid = threadIdx.x;
    int lane = tid & 63, w = tid >> 6;
    int wm = w >> 1, wn = w & 1;
    int rr = lane & 15, kg = lane >> 4;
    int bm = blockIdx.x * 128, bn = blockIdx.y * 128;

    f32x4 acc[4][4] = {};

    for (int k0 = 0; k0 < K; k0 += 32) {
#pragma unroll
        for (int s = 0; s < 2; ++s) {
            int c = tid + s * 256;
            int r = c >> 2, sl = c & 3;
            int ksrc = k0 + 8 * (sl ^ ((r >> 1) & 3));
            char* dstA = ((char*)As) + s * 4096 + w * 1024;
            char* dstB = ((char*)Bs) + s * 4096 + w * 1024;
            gload_lds16(A + (size_t)(bm + r) * K + ksrc, dstA);
            gload_lds16(Bt + (size_t)(bn + r) * K + ksrc, dstB);
        }
        __syncthreads();
        bf16x8 af[4], bfr[4];
#pragma unroll
        for (int i = 0; i < 4; ++i) {
            int row = wm * 64 + i * 16 + rr;
            af[i] = *(const bf16x8*)((const char*)As + row * 64 + ((kg ^ ((row >> 1) & 3)) << 4));
        }
#pragma unroll
        for (int j = 0; j < 4; ++j) {
            int col = wn * 64 + j * 16 + rr;
            bfr[j] = *(const bf16x8*)((const char*)Bs + col * 64 + ((kg ^ ((col >> 1) & 3)) << 4));
        }
#pragma unroll
        for (int i = 0; i < 4; ++i)
#pragma unroll
            for (int j = 0; j < 4; ++j)
                acc[i][j] = __builtin_amdgcn_mfma_f32_16x16x32_bf16(af[i], bfr[j], acc[i][j], 0, 0, 0);
        __syncthreads();
    }
#pragma unroll
    for (int i = 0; i < 4; ++i) {
#pragma unroll
        for (int j = 0; j < 4; ++j) {
            int col = bn + wn * 64 + j * 16 + rr;
#pragma unroll
            for (int q = 0; q < 4; ++q) {
                int row = bm + wm * 64 + i * 16 + kg * 4 + q;
                Cb[(size_t)row * NC + col] = __float2bfloat16(acc[i][j][q]);
            }
        }
    }
}

// ---------------- attention coefficients from bf16 xl ----------------

__global__ __launch_bounds__(256) void k_attn(const __hip_bfloat16* __restrict__ xlb,
                                              const float* __restrict__ as_,
                                              const float* __restrict__ ad_,
                                              float* __restrict__ als,
                                              float* __restrict__ ald, int n) {
    int node = (int)(((size_t)blockIdx.x * blockDim.x + threadIdx.x) >> 6);
    if (node >= n) return;
    int lane = threadIdx.x & 63;
    uint2 xv = *(const uint2*)(xlb + (size_t)node * 256 + (lane << 2));
    float x0 = bflo(xv.x), x1 = bfhi(xv.x), x2 = bflo(xv.y), x3 = bfhi(xv.y);
    float4 sv = *reinterpret_cast<const float4*>(as_ + (lane << 2));
    float4 dv = *reinterpret_cast<const float4*>(ad_ + (lane << 2));
    float ps = x0 * sv.x + x1 * sv.y + x2 * sv.z + x3 * sv.w;
    float pd = x0 * dv.x + x1 * dv.y + x2 * dv.z + x3 * dv.w;
#pragma unroll
    for (int off = 1; off < 8; off <<= 1) {
        ps += __shfl_xor(ps, off);
        pd += __shfl_xor(pd, off);
    }
    if ((lane & 7) == 0) {
        als[node * 8 + (lane >> 3)] = ps;
        ald[node * 8 + (lane >> 3)] = pd;
    }
}

// ---- pipelined aggregation: 8-edge chunks, alpha-once stats lanes, self-anchor ----
// stats: lane = 8*slot + h1 computes ONE alpha per chunk for (edge base+slot, head h1)
//        alpha = exp(lrelu(als+ald) - m0[h1]); m0 = self-loop logit (exact shift).
// gather: half = lane>>5 processes edges base+half+2t (t=0..3); lane owns 8 channels
//        ch0 = (lane&31)*8, head h2 = ch0>>5; alphas/sidx via shfl from stats lanes.
// Pipeline: csrc+als for chunk k+1 prefetched during chunk k's compute.

#define FMA8(XV, AL)                                              \
    {                                                             \
        acc[0] += (AL) * bflo(XV.x); acc[1] += (AL) * bfhi(XV.x); \
        acc[2] += (AL) * bflo(XV.y); acc[3] += (AL) * bfhi(XV.y); \
        acc[4] += (AL) * bflo(XV.z); acc[5] += (AL) * bfhi(XV.z); \
        acc[6] += (AL) * bflo(XV.w); acc[7] += (AL) * bfhi(XV.w); \
    }

__global__ __launch_bounds__(256) void k_agg(const __hip_bfloat16* __restrict__ xlb,
                                             const float* __restrict__ als,
                                             const float* __restrict__ ald,
                                             const int* __restrict__ rowptr,
                                             const int* __restrict__ csrc,
                                             const float* __restrict__ bias,
                                             __hip_bfloat16* __restrict__ hb,
                                             const float* __restrict__ w3,
                                             float* __restrict__ xl3, int n) {
    int node = (int)(((size_t)blockIdx.x * blockDim.x + threadIdx.x) >> 6);
    if (node >= n) return;
    int lane = threadIdx.x & 63;
    int beg = rowptr[node];
    int deg = rowptr[node + 1] - beg;
    int dm1 = deg - 1;

    int h1 = lane & 7, slot = lane >> 3;
    int half = lane >> 5;
    int l5 = lane & 31;
    int h2 = l5 >> 2;
    int ch0 = l5 << 3;
    const __hip_bfloat16* xrow = xlb + ch0;

    float aldv = ald[node * 8 + h1];
    float m0 = als[node * 8 + h1] + aldv;   // self-loop logit, head h1
    m0 = m0 > 0.f ? m0 : NEG_SLOPE * m0;    // exact exp-shift anchor

    float s = 0.f;
    float acc[8] = {};

    // preload chunk 0
    int sb = csrc[beg + min(slot, dm1)];
    float alsv = als[sb * 8 + h1];

    for (int base = 0; base < deg; base += 8) {
        int lim = deg - base;
        // broadcast sidx, issue current-chunk row gathers immediately
        int sx0 = __shfl(sb, (half + 0) << 3);
        int sx1 = __shfl(sb, (half + 2) << 3);
        int sx2 = __shfl(sb, (half + 4) << 3);
        int sx3 = __shfl(sb, (half + 6) << 3);
        uint4 xv0 = {}, xv1 = {}, xv2 = {}, xv3 = {};
        if (half + 0 < lim) xv0 = *(const uint4*)(xrow + ((size_t)sx0 << 8));
        if (half + 2 < lim) xv1 = *(const uint4*)(xrow + ((size_t)sx1 << 8));
        if (half + 4 < lim) xv2 = *(const uint4*)(xrow + ((size_t)sx2 << 8));
        if (half + 6 < lim) xv3 = *(const uint4*)(xrow + ((size_t)sx3 << 8));
        // prefetch next chunk's csrc
        int nb = base + 8;
        bool more = nb < deg;
        int sb_n = 0;
        if (more) sb_n = csrc[beg + min(nb + slot, dm1)];
        // alpha for this lane's (slot, h1) — no online rescale, anchor is fixed
        float e = alsv + aldv;
        e = e > 0.f ? e : NEG_SLOPE * e;
        float aval = (base + slot < deg) ? __expf(e - m0) : 0.f;
        s += aval;
        // prefetch next chunk's als
        float als_n = 0.f;
        if (more) als_n = als[sb_n * 8 + h1];
        // broadcast alphas to gather lanes, accumulate
        float a0 = __shfl(aval, ((half + 0) << 3) + h2);
        float a1 = __shfl(aval, ((half + 2) << 3) + h2);
        float a2 = __shfl(aval, ((half + 4) << 3) + h2);
        float a3 = __shfl(aval, ((half + 6) << 3) + h2);
        if (half + 0 < lim) FMA8(xv0, a0)
        if (half + 2 < lim) FMA8(xv1, a1)
        if (half + 4 < lim) FMA8(xv2, a2)
        if (half + 6 < lim) FMA8(xv3, a3)
        sb = sb_n;
        alsv = als_n;
    }
    // s: reduce over slots (lanes sharing h1); then all lanes hold head-h1 total
    s += __shfl_xor(s, 8);
    s += __shfl_xor(s, 16);
    s += __shfl_xor(s, 32);
    // acc: merge the two edge-halves
#pragma unroll
    for (int c = 0; c < 8; ++c) acc[c] += __shfl_xor(acc[c], 32);
    float inv = __shfl(1.f / (s + 1e-16f), h2);   // lane h2 holds head h2's s
    float o[8];
    float4 bv0 = *reinterpret_cast<const float4*>(bias + ch0);
    float4 bv1 = *reinterpret_cast<const float4*>(bias + ch0 + 4);
    o[0] = acc[0] * inv + bv0.x; o[1] = acc[1] * inv + bv0.y;
    o[2] = acc[2] * inv + bv0.z; o[3] = acc[3] * inv + bv0.w;
    o[4] = acc[4] * inv + bv1.x; o[5] = acc[5] * inv + bv1.y;
    o[6] = acc[6] * inv + bv1.z; o[7] = acc[7] * inv + bv1.w;
#pragma unroll
    for (int c = 0; c < 8; ++c) o[c] = o[c] > 0.f ? o[c] : expm1f(o[c]);

    if (w3) {
        // fused layer-3 matvec: half==0 lanes cover all 256 channels
        float p = 0.f;
        if (half == 0) {
#pragma unroll
            for (int c = 0; c < 8; ++c) p += o[c] * w3[ch0 + c];
        }
#pragma unroll
        for (int off = 1; off < 64; off <<= 1) p += __shfl_xor(p, off);
        if (lane == 0) xl3[node] = p;
    } else if (half == 0) {
        uint4 ov;
        ov.x = (unsigned)f2bf(o[0]) | ((unsigned)f2bf(o[1]) << 16);
        ov.y = (unsigned)f2bf(o[2]) | ((unsigned)f2bf(o[3]) << 16);
        ov.z = (unsigned)f2bf(o[4]) | ((unsigned)f2bf(o[5]) << 16);
        ov.w = (unsigned)f2bf(o[6]) | ((unsigned)f2bf(o[7]) << 16);
        *(uint4*)(hb + (size_t)node * 256 + ch0) = ov;
    }
}

// ---------------- layer 3 final ----------------

__global__ __launch_bounds__(256) void k_final(const float* __restrict__ xl3,
                                               const int* __restrict__ rowptr,
                                               const int* __restrict__ csrc,
                                               const float* __restrict__ as3,
                                               const float* __restrict__ ad3,
                                               const float* __restrict__ b3,
                                               float* __restrict__ out, int n) {
    int node = (int)(((size_t)blockIdx.x * blockDim.x + threadIdx.x) >> 6);
    if (node >= n) return;
    int lane = threadIdx.x & 63;
    int beg = rowptr[node];
    int deg = rowptr[node + 1] - beg;
    float a_s = as3[0], a_d = ad3[0], bb = b3[0];
    float xself = xl3[node];
    float dterm = a_d * xself;
    float m0 = a_s * xself + dterm;                 // self-loop logit anchor
    m0 = m0 > 0.f ? m0 : NEG_SLOPE * m0;
    float s = 0.f, wv = 0.f;
    for (int ee = lane; ee < deg; ee += 64) {
        int sidx = csrc[beg + ee];
        float xs = xl3[sidx];
        float e = a_s * xs + dterm;
        e = e > 0.f ? e : NEG_SLOPE * e;
        float ex = __expf(e - m0);
        s += ex;
        wv += ex * xs;
    }
#pragma unroll
    for (int off = 1; off < 64; off <<= 1) {
        s += __shfl_xor(s, off);
        wv += __shfl_xor(wv, off);
    }
    if (lane == 0) out[node] = wv / (s + 1e-16f) + bb;
}

// ---------------- launcher ----------------

extern "C" void kernel_launch(void* const* d_in, const int* in_sizes, int n_in,
                              void* d_out, int out_size, void* d_ws, size_t ws_size,
                              hipStream_t stream) {
    const float* x   = (const float*)d_in[0];
    const int*   ei  = (const int*)d_in[1];
    const float* W0  = (const float*)d_in[2];
    const float* as0 = (const float*)d_in[3];
    const float* ad0 = (const float*)d_in[4];
    const float* b0  = (const float*)d_in[5];
    const float* W1  = (const float*)d_in[6];
    const float* as1 = (const float*)d_in[7];
    const float* ad1 = (const float*)d_in[8];
    const float* b1  = (const float*)d_in[9];
    const float* W2  = (const float*)d_in[10];
    const float* as2 = (const float*)d_in[11];
    const float* ad2 = (const float*)d_in[12];
    const float* b2  = (const float*)d_in[13];
    const float* W3  = (const float*)d_in[14];
    const float* as3 = (const float*)d_in[15];
    const float* ad3 = (const float*)d_in[16];
    const float* b3  = (const float*)d_in[17];

    int N    = in_sizes[0] / 64;   // 30000
    int E    = in_sizes[1] / 2;    // 480000
    int K0   = in_sizes[2] / 256;  // 64
    int Npad = (N + 127) & ~127;   // 30080

    char* ws = (char*)d_ws;
    auto alloc = [&](size_t bytes) {
        char* p = ws;
        ws += (bytes + 255) & ~(size_t)255;
        return p;
    };
    int* rowptr = (int*)alloc((size_t)(N + 1) * 4);
    int* cc     = (int*)alloc((size_t)2 * N * 4);  // cursor | counts
    int* cursor = cc;
    int* counts = cc + N;
    int* csrc   = (int*)alloc((size_t)(E + N) * 4);
    __hip_bfloat16* xb  = (__hip_bfloat16*)alloc((size_t)Npad * K0 * 2);
    __hip_bfloat16* W0t = (__hip_bfloat16*)alloc((size_t)K0 * 256 * 2);
    __hip_bfloat16* W1t = (__hip_bfloat16*)alloc((size_t)256 * 256 * 2);
    __hip_bfloat16* W2t = (__hip_bfloat16*)alloc((size_t)256 * 256 * 2);
    __hip_bfloat16* xlb = (__hip_bfloat16*)alloc((size_t)Npad * 256 * 2);
    __hip_bfloat16* hb  = (__hip_bfloat16*)alloc((size_t)Npad * 256 * 2);
    float* als = (float*)alloc((size_t)N * 8 * 4);
    float* ald = (float*)alloc((size_t)N * 8 * 4);
    float* xl3 = (float*)alloc((size_t)N * 4);

    hipMemsetAsync(cc, 0, (size_t)2 * N * 4, stream);
    hipMemsetAsync(hb + (size_t)N * 256, 0, (size_t)(Npad - N) * 256 * 2, stream);

    int totA = Npad * K0;
    int totPrep = totA + K0 * 256 + 65536 + 65536;
    k_prep<<<(totPrep + E + 255) / 256, 256, 0, stream>>>(x, W0, W1, W2, xb, W0t, W1t, W2t,
                                                          ei, counts, E, N, K0, totA, totPrep);
    k_scan<<<1, 1024, 0, stream>>>(counts, rowptr, N);
    k_scatter<<<(E + N + 255) / 256, 256, 0, stream>>>(ei, E, N, rowptr, cursor, csrc);

    int nwb = (N + 3) / 4;        // 1 wave/node, 4 waves/block
    dim3 ggrid(Npad / 128, 2);

    // layer 0
    k_gemm_mfma<<<ggrid, 256, 0, stream>>>(xb, W0t, xlb, K0, 256);
    k_attn<<<nwb, 256, 0, stream>>>(xlb, as0, ad0, als, ald, N);
    k_agg<<<nwb, 256, 0, stream>>>(xlb, als, ald, rowptr, csrc, b0, hb, nullptr, nullptr, N);
    // layer 1
    k_gemm_mfma<<<ggrid, 256, 0, stream>>>(hb, W1t, xlb, 256, 256);
    k_attn<<<nwb, 256, 0, stream>>>(xlb, as1, ad1, als, ald, N);
    k_agg<<<nwb, 256, 0, stream>>>(xlb, als, ald, rowptr, csrc, b1, hb, nullptr, nullptr, N);
    // layer 2 (+ fused layer-3 matvec)
    k_gemm_mfma<<<ggrid, 256, 0, stream>>>(hb, W2t, xlb, 256, 256);
    k_attn<<<nwb, 256, 0, stream>>>(xlb, as2, ad2, als, ald, N);
    k_agg<<<nwb, 256, 0, stream>>>(xlb, als, ald, rowptr, csrc, b2, hb, W3, xl3, N);
    // layer 3
    k_final<<<nwb, 256, 0, stream>>>(xl3, rowptr, csrc, as3, ad3, b3, (float*)d_out, N);
}